// Round 3
// baseline (439.769 us; speedup 1.0000x reference)
//
#include <hip/hip_runtime.h>
#include <hip/hip_bf16.h>

#define NPTS 262144              // output rows (2^18)
#define MRB  131072              // rulebook entries per offset (2^17)
#define KOFF 9
#define NENT (KOFF * MRB)        // 1,179,648 total entries

typedef __attribute__((ext_vector_type(8))) short short8;
typedef __attribute__((ext_vector_type(4))) short short4v;
typedef __attribute__((ext_vector_type(4))) float f32x4;

__device__ __forceinline__ short f2bf(float f) {
    __hip_bfloat16 h = __float2bfloat16(f);
    return __builtin_bit_cast(short, h);
}
__device__ __forceinline__ float bf2f(unsigned short u) {
    unsigned int x = ((unsigned int)u) << 16;
    return __builtin_bit_cast(float, x);
}
__device__ __forceinline__ void atomic_add_f32(float* p, float v) {
    __hip_atomic_fetch_add(p, v, __ATOMIC_RELAXED, __HIP_MEMORY_SCOPE_AGENT);
}

// ---------------- ws layout (fast path) ----------------
#define PROD_OFF   0ull                                   // bf16 [NENT][64]
#define POS_OFF    150994944ull                           // int  [NENT]
#define START_OFF  155713536ull                           // int  [NPTS+1]
#define CURSOR_OFF 156762368ull                           // int  [NPTS]
#define COUNTS_OFF 157810944ull                           // int  [NPTS]
#define BSUM_OFF   158859520ull                           // int  [256]
#define WS_NEED    158860544ull

// ============================================================
// Fast path kernels
// ============================================================

// coords -> float into d_out[0:3N); zero the histogram counters.
__global__ __launch_bounds__(256) void init_fast(const int* __restrict__ coords,
                                                 float* __restrict__ out,
                                                 int* __restrict__ counts) {
    const int i = blockIdx.x * 256 + threadIdx.x;   // grid = 1024 blocks -> 262144
    const int nc4 = (NPTS * 3) / 4;                 // 196608
    if (i < nc4) {
        int4 c = ((const int4*)coords)[i];
        float4 f;
        f.x = (float)c.x; f.y = (float)c.y; f.z = (float)c.z; f.w = (float)c.w;
        ((float4*)out)[i] = f;
    } else {
        int j = i - nc4;                            // [0, 65536)
        ((int4*)counts)[j] = make_int4(0, 0, 0, 0);
    }
}

__global__ __launch_bounds__(256) void hist_kernel(const int* __restrict__ out_rows,
                                                   int* __restrict__ counts) {
    const int e = blockIdx.x * 256 + threadIdx.x;   // grid = 4608 -> NENT exact
    atomicAdd(&counts[out_rows[e]], 1);
}

// Block-level exclusive scan: 256 blocks x 1024 elements.
__global__ __launch_bounds__(1024) void scan_blocks(const int* __restrict__ counts,
                                                    int* __restrict__ start,
                                                    int* __restrict__ bsum) {
    __shared__ int lds[1024];
    const int tid = threadIdx.x;
    const int gid = blockIdx.x * 1024 + tid;
    int v = counts[gid];
    lds[tid] = v;
    __syncthreads();
#pragma unroll
    for (int off = 1; off < 1024; off <<= 1) {
        int t = (tid >= off) ? lds[tid - off] : 0;
        __syncthreads();
        lds[tid] += t;
        __syncthreads();
    }
    start[gid] = lds[tid] - v;                      // exclusive within block
    if (tid == 1023) bsum[blockIdx.x] = lds[tid];   // block total
}

// Exclusive scan of the 256 block sums (single block).
__global__ __launch_bounds__(256) void scan_bsum(int* __restrict__ bsum) {
    __shared__ int lds[256];
    const int tid = threadIdx.x;
    int v = bsum[tid];
    lds[tid] = v;
    __syncthreads();
#pragma unroll
    for (int off = 1; off < 256; off <<= 1) {
        int t = (tid >= off) ? lds[tid - off] : 0;
        __syncthreads();
        lds[tid] += t;
        __syncthreads();
    }
    bsum[tid] = lds[tid] - v;                       // exclusive
}

__global__ __launch_bounds__(1024) void add_offsets(int* __restrict__ start,
                                                    const int* __restrict__ bsum,
                                                    int* __restrict__ cursor) {
    const int gid = blockIdx.x * 1024 + threadIdx.x;
    int s = start[gid] + bsum[blockIdx.x];
    start[gid] = s;
    cursor[gid] = s;
    if (gid == 0) start[NPTS] = NENT;
}

__global__ __launch_bounds__(256) void fill_pos(const int* __restrict__ out_rows,
                                                int* __restrict__ cursor,
                                                int* __restrict__ pos) {
    const int e = blockIdx.x * 256 + threadIdx.x;   // grid = 4608
    pos[e] = atomicAdd(&cursor[out_rows[e]], 1);
}

// MFMA gather-GEMM, transposed D (lane holds one entry, 4 consecutive channels
// per mt).  Writes each entry's 64-ch product row (bf16) to its sorted slot.
//   A = W^T frag: wfrag[kk][mt][j] = W[kk*32+lhi*8+j][mt*16+lrow]
//   B = feats frag: entry = mb+lrow, k-chunk = kk*32+lhi*8+{0..7}
//   D: col(entry) = lane&15, row(channel within mt) = 4*lhi + r
__global__ __launch_bounds__(256) void conv_prod(const float* __restrict__ feats,
                                                 const int*   __restrict__ in_rows,
                                                 const float* __restrict__ weight,
                                                 const int*   __restrict__ pos,
                                                 short*       __restrict__ prod) {
    const int lane = threadIdx.x & 63;
    const int wv   = threadIdx.x >> 6;
    const int lrow = lane & 15;
    const int lhi  = lane >> 4;
    const int BPK  = MRB / 64;                      // 2048 blocks per offset
    const int k    = blockIdx.x / BPK;
    const int mb   = (blockIdx.x % BPK) * 64 + wv * 16;

    const float* Wk = weight + k * 64 * 64;
    short8 wfrag[2][4];
#pragma unroll
    for (int kk = 0; kk < 2; ++kk)
#pragma unroll
        for (int mt = 0; mt < 4; ++mt)
#pragma unroll
            for (int j = 0; j < 8; ++j)
                wfrag[kk][mt][j] = f2bf(Wk[(kk * 32 + lhi * 8 + j) * 64 + mt * 16 + lrow]);

    const int e    = k * MRB + mb + lrow;
    const int arow = in_rows[e];
    const float* ap = feats + (long)arow * 64 + lhi * 8;

    f32x4 acc[4] = {};
#pragma unroll
    for (int kk = 0; kk < 2; ++kk) {
        float4 f0 = *(const float4*)(ap + kk * 32);
        float4 f1 = *(const float4*)(ap + kk * 32 + 4);
        short8 ffrag;
        ffrag[0] = f2bf(f0.x); ffrag[1] = f2bf(f0.y);
        ffrag[2] = f2bf(f0.z); ffrag[3] = f2bf(f0.w);
        ffrag[4] = f2bf(f1.x); ffrag[5] = f2bf(f1.y);
        ffrag[6] = f2bf(f1.z); ffrag[7] = f2bf(f1.w);
#pragma unroll
        for (int mt = 0; mt < 4; ++mt)
            acc[mt] = __builtin_amdgcn_mfma_f32_16x16x32_bf16(wfrag[kk][mt], ffrag, acc[mt], 0, 0, 0);
    }

    const int p = pos[e];
    short* pp = prod + (size_t)p * 64 + lhi * 4;    // channels lhi*4 + mt*16 + r
#pragma unroll
    for (int mt = 0; mt < 4; ++mt) {
        short4v s;
        s[0] = f2bf(acc[mt][0]); s[1] = f2bf(acc[mt][1]);
        s[2] = f2bf(acc[mt][2]); s[3] = f2bf(acc[mt][3]);
        *(short4v*)(pp + mt * 16) = s;
    }
}

// Per output row: sum the contiguous slot segment, add bias, store f32.
__global__ __launch_bounds__(256) void reduce_out(const short* __restrict__ prod,
                                                  const int*   __restrict__ start,
                                                  const float* __restrict__ bias,
                                                  float*       __restrict__ out) {
    const int lane = threadIdx.x & 63;
    const int wid  = (blockIdx.x * 256 + threadIdx.x) >> 6;
    const int nw   = (gridDim.x * 256) >> 6;
    const float b  = bias[lane];
    for (int r = wid; r < NPTS; r += nw) {
        const int s0 = start[r], s1 = start[r + 1];
        float acc = 0.f;
        const unsigned short* p = (const unsigned short*)prod + (size_t)s0 * 64 + lane;
        for (int s = s0; s < s1; ++s, p += 64)
            acc += bf2f(*p);
        out[(size_t)r * 64 + lane] = acc + b;
    }
}

// ============================================================
// Fallback path (round-1 verified): scalar-atomic scatter
// ============================================================
__global__ __launch_bounds__(256) void init_full(const int* __restrict__ coords,
                                                 const float* __restrict__ bias,
                                                 float* __restrict__ out) {
    const int tid = blockIdx.x * blockDim.x + threadIdx.x;
    const int nc4 = (NPTS * 3) / 4;
    const int nf4 = (NPTS * 64) / 4;
    for (int i = tid; i < nc4 + nf4; i += gridDim.x * blockDim.x) {
        if (i < nc4) {
            int4 c = ((const int4*)coords)[i];
            float4 f;
            f.x = (float)c.x; f.y = (float)c.y; f.z = (float)c.z; f.w = (float)c.w;
            ((float4*)out)[i] = f;
        } else {
            int j = i - nc4;
            float4 b = ((const float4*)bias)[j & 15];
            ((float4*)(out + (size_t)NPTS * 3))[j] = b;
        }
    }
}

__global__ __launch_bounds__(256) void conv_atomic(const float* __restrict__ feats,
                                                   const int*   __restrict__ in_rows,
                                                   const int*   __restrict__ out_rows,
                                                   const float* __restrict__ weight,
                                                   float*       __restrict__ out) {
    const int lane = threadIdx.x & 63;
    const int wv   = threadIdx.x >> 6;
    const int lrow = lane & 15;
    const int lhi  = lane >> 4;
    const int BPK  = MRB / 64;
    const int k    = blockIdx.x / BPK;
    const int mb   = (blockIdx.x % BPK) * 64 + wv * 16;

    const float* Wk = weight + k * 64 * 64;
    short8 bfrag[2][4];
#pragma unroll
    for (int kk = 0; kk < 2; ++kk)
#pragma unroll
        for (int nt = 0; nt < 4; ++nt)
#pragma unroll
            for (int j = 0; j < 8; ++j)
                bfrag[kk][nt][j] = f2bf(Wk[(kk * 32 + lhi * 8 + j) * 64 + nt * 16 + lrow]);

    const int arow = in_rows[k * MRB + mb + lrow];
    const float* ap = feats + (long)arow * 64 + lhi * 8;

    f32x4 acc[4] = {};
#pragma unroll
    for (int kk = 0; kk < 2; ++kk) {
        float4 f0 = *(const float4*)(ap + kk * 32);
        float4 f1 = *(const float4*)(ap + kk * 32 + 4);
        short8 afrag;
        afrag[0] = f2bf(f0.x); afrag[1] = f2bf(f0.y);
        afrag[2] = f2bf(f0.z); afrag[3] = f2bf(f0.w);
        afrag[4] = f2bf(f1.x); afrag[5] = f2bf(f1.y);
        afrag[6] = f2bf(f1.z); afrag[7] = f2bf(f1.w);
#pragma unroll
        for (int nt = 0; nt < 4; ++nt)
            acc[nt] = __builtin_amdgcn_mfma_f32_16x16x32_bf16(afrag, bfrag[kk][nt], acc[nt], 0, 0, 0);
    }

    const int ob = k * MRB + mb + lhi * 4;
#pragma unroll
    for (int r = 0; r < 4; ++r) {
        const int orow = out_rows[ob + r];
        float* op = out + (long)orow * 64 + lrow;
#pragma unroll
        for (int nt = 0; nt < 4; ++nt)
            atomic_add_f32(op + nt * 16, acc[nt][r]);
    }
}

// ============================================================
extern "C" void kernel_launch(void* const* d_in, const int* in_sizes, int n_in,
                              void* d_out, int out_size, void* d_ws, size_t ws_size,
                              hipStream_t stream) {
    const int*   coords   = (const int*)  d_in[0];
    const float* feats    = (const float*)d_in[1];
    const int*   in_rows  = (const int*)  d_in[2];
    const int*   out_rows = (const int*)  d_in[3];
    const float* weight   = (const float*)d_in[4];
    const float* bias     = (const float*)d_in[5];
    float* out      = (float*)d_out;
    float* out_feat = out + (size_t)NPTS * 3;

    if (ws_size >= WS_NEED) {
        char* ws = (char*)d_ws;
        short* prod  = (short*)(ws + PROD_OFF);
        int* pos     = (int*)(ws + POS_OFF);
        int* start   = (int*)(ws + START_OFF);
        int* cursor  = (int*)(ws + CURSOR_OFF);
        int* counts  = (int*)(ws + COUNTS_OFF);
        int* bsum    = (int*)(ws + BSUM_OFF);

        hipLaunchKernelGGL(init_fast,   dim3(1024), dim3(256),  0, stream, coords, out, counts);
        hipLaunchKernelGGL(hist_kernel, dim3(NENT / 256), dim3(256), 0, stream, out_rows, counts);
        hipLaunchKernelGGL(scan_blocks, dim3(NPTS / 1024), dim3(1024), 0, stream, counts, start, bsum);
        hipLaunchKernelGGL(scan_bsum,   dim3(1),    dim3(256),  0, stream, bsum);
        hipLaunchKernelGGL(add_offsets, dim3(NPTS / 1024), dim3(1024), 0, stream, start, bsum, cursor);
        hipLaunchKernelGGL(fill_pos,    dim3(NENT / 256), dim3(256), 0, stream, out_rows, cursor, pos);
        hipLaunchKernelGGL(conv_prod,   dim3(KOFF * (MRB / 64)), dim3(256), 0, stream,
                           feats, in_rows, weight, pos, prod);
        hipLaunchKernelGGL(reduce_out,  dim3(2048), dim3(256),  0, stream, prod, start, bias, out_feat);
    } else {
        hipLaunchKernelGGL(init_full,  dim3(2048), dim3(256), 0, stream, coords, bias, out);
        hipLaunchKernelGGL(conv_atomic, dim3(KOFF * (MRB / 64)), dim3(256), 0, stream,
                           feats, in_rows, out_rows, weight, out_feat);
    }
}

// Round 4
// 416.272 us; speedup vs baseline: 1.0564x; 1.0564x over previous
//
#include <hip/hip_runtime.h>
#include <hip/hip_bf16.h>

#define NPTS 262144              // output rows (2^18)
#define MRB  131072              // rulebook entries per offset (2^17)
#define KOFF 9
#define NENT (KOFF * MRB)        // 1,179,648 total entries

typedef __attribute__((ext_vector_type(8))) short short8;
typedef __attribute__((ext_vector_type(4))) short short4v;
typedef __attribute__((ext_vector_type(4))) float f32x4;

__device__ __forceinline__ short f2bf(float f) {
    __hip_bfloat16 h = __float2bfloat16(f);
    return __builtin_bit_cast(short, h);
}
__device__ __forceinline__ float bf2f(unsigned short u) {
    unsigned int x = ((unsigned int)u) << 16;
    return __builtin_bit_cast(float, x);
}
__device__ __forceinline__ void atomic_add_f32(float* p, float v) {
    __hip_atomic_fetch_add(p, v, __ATOMIC_RELAXED, __HIP_MEMORY_SCOPE_AGENT);
}

// ---------------- ws layout (fast path) ----------------
#define FB_OFF     0ull                  // bf16 [NPTS][64]      33,554,432 B
#define WBF_OFF    33554432ull           // bf16 frag-layout W     73,728 B
#define PROD_OFF   33628160ull           // bf16 [NENT][64]     150,994,944 B
#define IDX_OFF    184623104ull          // int  [NENT]           4,718,592 B
#define START_OFF  189341696ull          // int  [NPTS+1] (+pad)  1,048,832 B
#define CURSOR_OFF 190390528ull          // int  [NPTS]           1,048,576 B
#define COUNTS_OFF 191439104ull          // int  [NPTS]           1,048,576 B
#define BSUM_OFF   192487680ull          // int  [256]
#define WS_NEED    192488704ull

// ============================================================
// Fast path kernels
// ============================================================

// One grid-stride kernel: coords->float, zero counts, feats->bf16,
// weight->bf16 in exact MFMA fragment layout.
__global__ __launch_bounds__(256) void prep(const int*   __restrict__ coords,
                                            const float* __restrict__ feats,
                                            const float* __restrict__ weight,
                                            float* __restrict__ out,
                                            int*   __restrict__ counts,
                                            short* __restrict__ fb,
                                            short* __restrict__ wbf) {
    const int T0 = (NPTS * 3) / 4;        // 196608  coords int4
    const int T1 = T0 + NPTS / 4;         // +65536  counts int4 zero
    const int T2 = T1 + NPTS * 16;        // +4194304 feats float4->short4
    const int T3 = T2 + (KOFF * 8 * 64);  // +4608   weight frag groups
    const int stride = gridDim.x * 256;
    for (int i = blockIdx.x * 256 + threadIdx.x; i < T3; i += stride) {
        if (i < T0) {
            int4 c = ((const int4*)coords)[i];
            float4 f;
            f.x = (float)c.x; f.y = (float)c.y; f.z = (float)c.z; f.w = (float)c.w;
            ((float4*)out)[i] = f;
        } else if (i < T1) {
            ((int4*)counts)[i - T0] = make_int4(0, 0, 0, 0);
        } else if (i < T2) {
            int j = i - T1;
            float4 f = ((const float4*)feats)[j];
            short4v s;
            s[0] = f2bf(f.x); s[1] = f2bf(f.y); s[2] = f2bf(f.z); s[3] = f2bf(f.w);
            ((short4v*)fb)[j] = s;
        } else {
            int w    = i - T2;            // [0, 4608)
            int lane = w & 63;
            int g    = w >> 6;            // g = k*8 + kk*4 + mt, [0,72)
            int mt   = g & 3, kk = (g >> 2) & 1, k = g >> 3;
            int lhi  = lane >> 4, lrow = lane & 15;
            const float* Wk = weight + k * 64 * 64;
            short8 v;
#pragma unroll
            for (int j = 0; j < 8; ++j)
                v[j] = f2bf(Wk[(kk * 32 + lhi * 8 + j) * 64 + mt * 16 + lrow]);
            ((short8*)wbf)[g * 64 + lane] = v;
        }
    }
}

__global__ __launch_bounds__(256) void hist_kernel(const int* __restrict__ out_rows,
                                                   int* __restrict__ counts) {
    const int e = blockIdx.x * 256 + threadIdx.x;   // grid = 4608
    atomicAdd(&counts[out_rows[e]], 1);
}

__global__ __launch_bounds__(1024) void scan_blocks(const int* __restrict__ counts,
                                                    int* __restrict__ start,
                                                    int* __restrict__ bsum) {
    __shared__ int lds[1024];
    const int tid = threadIdx.x;
    const int gid = blockIdx.x * 1024 + tid;
    int v = counts[gid];
    lds[tid] = v;
    __syncthreads();
#pragma unroll
    for (int off = 1; off < 1024; off <<= 1) {
        int t = (tid >= off) ? lds[tid - off] : 0;
        __syncthreads();
        lds[tid] += t;
        __syncthreads();
    }
    start[gid] = lds[tid] - v;
    if (tid == 1023) bsum[blockIdx.x] = lds[tid];
}

__global__ __launch_bounds__(256) void scan_bsum(int* __restrict__ bsum) {
    __shared__ int lds[256];
    const int tid = threadIdx.x;
    int v = bsum[tid];
    lds[tid] = v;
    __syncthreads();
#pragma unroll
    for (int off = 1; off < 256; off <<= 1) {
        int t = (tid >= off) ? lds[tid - off] : 0;
        __syncthreads();
        lds[tid] += t;
        __syncthreads();
    }
    bsum[tid] = lds[tid] - v;
}

__global__ __launch_bounds__(1024) void add_offsets(int* __restrict__ start,
                                                    const int* __restrict__ bsum,
                                                    int* __restrict__ cursor) {
    const int gid = blockIdx.x * 1024 + threadIdx.x;
    int s = start[gid] + bsum[blockIdx.x];
    start[gid] = s;
    cursor[gid] = s;
    if (gid == 0) start[NPTS] = NENT;
}

// Inverted index: idx[slot] = entry id, slots of one out row contiguous.
__global__ __launch_bounds__(256) void fill_idx(const int* __restrict__ out_rows,
                                                int* __restrict__ cursor,
                                                int* __restrict__ idx) {
    const int e = blockIdx.x * 256 + threadIdx.x;   // grid = 4608
    idx[atomicAdd(&cursor[out_rows[e]], 1)] = e;
}

// Gather-GEMM, transposed D; PURE STREAM writes in entry order (no pos).
//   wfrag[kk][mt]: one 16-B L1-hot load from the pre-laid-out wbf.
//   ffrag: one 16-B load per kk from bf16 feats (gather, 128 B/row).
//   D: col(entry)=lane&15, channel = mt*16 + 4*(lane>>4) + r.
__global__ __launch_bounds__(256) void conv_prod(const short* __restrict__ fb,
                                                 const int*   __restrict__ in_rows,
                                                 const short* __restrict__ wbf,
                                                 short*       __restrict__ prod) {
    const int lane = threadIdx.x & 63;
    const int wv   = threadIdx.x >> 6;
    const int lrow = lane & 15;
    const int lhi  = lane >> 4;
    const int BPK  = MRB / 64;                      // 2048 blocks per offset
    const int k    = blockIdx.x / BPK;
    const int mb   = (blockIdx.x % BPK) * 64 + wv * 16;

    short8 wfrag[2][4];
#pragma unroll
    for (int kk = 0; kk < 2; ++kk)
#pragma unroll
        for (int mt = 0; mt < 4; ++mt)
            wfrag[kk][mt] = ((const short8*)wbf)[(k * 8 + kk * 4 + mt) * 64 + lane];

    const int e    = k * MRB + mb + lrow;
    const int arow = in_rows[e];
    const short* ap = fb + (size_t)arow * 64 + lhi * 8;

    f32x4 acc[4] = {};
#pragma unroll
    for (int kk = 0; kk < 2; ++kk) {
        short8 ffrag = *(const short8*)(ap + kk * 32);
#pragma unroll
        for (int mt = 0; mt < 4; ++mt)
            acc[mt] = __builtin_amdgcn_mfma_f32_16x16x32_bf16(wfrag[kk][mt], ffrag, acc[mt], 0, 0, 0);
    }

    short* pp = prod + (size_t)e * 64 + lhi * 4;
#pragma unroll
    for (int mt = 0; mt < 4; ++mt) {
        short4v s;
        s[0] = f2bf(acc[mt][0]); s[1] = f2bf(acc[mt][1]);
        s[2] = f2bf(acc[mt][2]); s[3] = f2bf(acc[mt][3]);
        *(short4v*)(pp + mt * 16) = s;
    }
}

// One wave per row (grid-stride): 4 slots/iteration.
//   lane = (slot-phase = lane>>4) x (channel-quad = lane&15)
//   8-B short4 loads -> 512 B per wave-iteration; shfl_xor(16,32) combine;
//   lanes 0-15 store float4 (+bias). Rows with 0 slots get pure bias.
__global__ __launch_bounds__(256) void reduce_out(const short* __restrict__ prod,
                                                  const int*   __restrict__ idx,
                                                  const int*   __restrict__ start,
                                                  const float* __restrict__ bias,
                                                  float*       __restrict__ out) {
    const int lane  = threadIdx.x & 63;
    const int lrow  = lane & 15;
    const int phase = lane >> 4;
    const int wid   = (blockIdx.x * 256 + threadIdx.x) >> 6;
    const int nw    = (gridDim.x * 256) >> 6;
    const float4 b4 = ((const float4*)bias)[lrow];

    for (int r = wid; r < NPTS; r += nw) {
        const int s0 = start[r], s1 = start[r + 1];
        f32x4 a = {};
        for (int s = s0 + phase; s < s1; s += 4) {
            const int e = idx[s];
            short4v v = *(const short4v*)(prod + (size_t)e * 64 + lrow * 4);
            a[0] += bf2f((unsigned short)v[0]);
            a[1] += bf2f((unsigned short)v[1]);
            a[2] += bf2f((unsigned short)v[2]);
            a[3] += bf2f((unsigned short)v[3]);
        }
#pragma unroll
        for (int c = 0; c < 4; ++c) {
            a[c] += __shfl_xor(a[c], 16);
            a[c] += __shfl_xor(a[c], 32);
        }
        if (lane < 16) {
            float4 o;
            o.x = a[0] + b4.x; o.y = a[1] + b4.y;
            o.z = a[2] + b4.z; o.w = a[3] + b4.w;
            ((float4*)(out + (size_t)r * 64))[lrow] = o;
        }
    }
}

// ============================================================
// Fallback path (round-1 verified): scalar-atomic scatter
// ============================================================
__global__ __launch_bounds__(256) void init_full(const int* __restrict__ coords,
                                                 const float* __restrict__ bias,
                                                 float* __restrict__ out) {
    const int tid = blockIdx.x * blockDim.x + threadIdx.x;
    const int nc4 = (NPTS * 3) / 4;
    const int nf4 = (NPTS * 64) / 4;
    for (int i = tid; i < nc4 + nf4; i += gridDim.x * blockDim.x) {
        if (i < nc4) {
            int4 c = ((const int4*)coords)[i];
            float4 f;
            f.x = (float)c.x; f.y = (float)c.y; f.z = (float)c.z; f.w = (float)c.w;
            ((float4*)out)[i] = f;
        } else {
            int j = i - nc4;
            float4 b = ((const float4*)bias)[j & 15];
            ((float4*)(out + (size_t)NPTS * 3))[j] = b;
        }
    }
}

__global__ __launch_bounds__(256) void conv_atomic(const float* __restrict__ feats,
                                                   const int*   __restrict__ in_rows,
                                                   const int*   __restrict__ out_rows,
                                                   const float* __restrict__ weight,
                                                   float*       __restrict__ out) {
    const int lane = threadIdx.x & 63;
    const int wv   = threadIdx.x >> 6;
    const int lrow = lane & 15;
    const int lhi  = lane >> 4;
    const int BPK  = MRB / 64;
    const int k    = blockIdx.x / BPK;
    const int mb   = (blockIdx.x % BPK) * 64 + wv * 16;

    const float* Wk = weight + k * 64 * 64;
    short8 bfrag[2][4];
#pragma unroll
    for (int kk = 0; kk < 2; ++kk)
#pragma unroll
        for (int nt = 0; nt < 4; ++nt)
#pragma unroll
            for (int j = 0; j < 8; ++j)
                bfrag[kk][nt][j] = f2bf(Wk[(kk * 32 + lhi * 8 + j) * 64 + nt * 16 + lrow]);

    const int arow = in_rows[k * MRB + mb + lrow];
    const float* ap = feats + (long)arow * 64 + lhi * 8;

    f32x4 acc[4] = {};
#pragma unroll
    for (int kk = 0; kk < 2; ++kk) {
        float4 f0 = *(const float4*)(ap + kk * 32);
        float4 f1 = *(const float4*)(ap + kk * 32 + 4);
        short8 afrag;
        afrag[0] = f2bf(f0.x); afrag[1] = f2bf(f0.y);
        afrag[2] = f2bf(f0.z); afrag[3] = f2bf(f0.w);
        afrag[4] = f2bf(f1.x); afrag[5] = f2bf(f1.y);
        afrag[6] = f2bf(f1.z); afrag[7] = f2bf(f1.w);
#pragma unroll
        for (int nt = 0; nt < 4; ++nt)
            acc[nt] = __builtin_amdgcn_mfma_f32_16x16x32_bf16(afrag, bfrag[kk][nt], acc[nt], 0, 0, 0);
    }

    const int ob = k * MRB + mb + lhi * 4;
#pragma unroll
    for (int r = 0; r < 4; ++r) {
        const int orow = out_rows[ob + r];
        float* op = out + (long)orow * 64 + lrow;
#pragma unroll
        for (int nt = 0; nt < 4; ++nt)
            atomic_add_f32(op + nt * 16, acc[nt][r]);
    }
}

// ============================================================
extern "C" void kernel_launch(void* const* d_in, const int* in_sizes, int n_in,
                              void* d_out, int out_size, void* d_ws, size_t ws_size,
                              hipStream_t stream) {
    const int*   coords   = (const int*)  d_in[0];
    const float* feats    = (const float*)d_in[1];
    const int*   in_rows  = (const int*)  d_in[2];
    const int*   out_rows = (const int*)  d_in[3];
    const float* weight   = (const float*)d_in[4];
    const float* bias     = (const float*)d_in[5];
    float* out      = (float*)d_out;
    float* out_feat = out + (size_t)NPTS * 3;

    if (ws_size >= WS_NEED) {
        char* ws = (char*)d_ws;
        short* fb    = (short*)(ws + FB_OFF);
        short* wbf   = (short*)(ws + WBF_OFF);
        short* prod  = (short*)(ws + PROD_OFF);
        int* idx     = (int*)(ws + IDX_OFF);
        int* start   = (int*)(ws + START_OFF);
        int* cursor  = (int*)(ws + CURSOR_OFF);
        int* counts  = (int*)(ws + COUNTS_OFF);
        int* bsum    = (int*)(ws + BSUM_OFF);

        hipLaunchKernelGGL(prep,        dim3(2048), dim3(256), 0, stream,
                           coords, feats, weight, out, counts, fb, wbf);
        hipLaunchKernelGGL(hist_kernel, dim3(NENT / 256), dim3(256), 0, stream, out_rows, counts);
        hipLaunchKernelGGL(scan_blocks, dim3(NPTS / 1024), dim3(1024), 0, stream, counts, start, bsum);
        hipLaunchKernelGGL(scan_bsum,   dim3(1), dim3(256), 0, stream, bsum);
        hipLaunchKernelGGL(add_offsets, dim3(NPTS / 1024), dim3(1024), 0, stream, start, bsum, cursor);
        hipLaunchKernelGGL(fill_idx,    dim3(NENT / 256), dim3(256), 0, stream, out_rows, cursor, idx);
        hipLaunchKernelGGL(conv_prod,   dim3(KOFF * (MRB / 64)), dim3(256), 0, stream,
                           fb, in_rows, wbf, prod);
        hipLaunchKernelGGL(reduce_out,  dim3(2048), dim3(256), 0, stream,
                           prod, idx, start, bias, out_feat);
    } else {
        hipLaunchKernelGGL(init_full,   dim3(2048), dim3(256), 0, stream, coords, bias, out);
        hipLaunchKernelGGL(conv_atomic, dim3(KOFF * (MRB / 64)), dim3(256), 0, stream,
                           feats, in_rows, out_rows, weight, out_feat);
    }
}